// Round 3
// baseline (302.553 us; speedup 1.0000x reference)
//
#include <hip/hip_runtime.h>
#include <math.h>

#ifndef M_PI
#define M_PI 3.14159265358979323846
#endif

#define BSZ 16
#define SEQ 4096
#define DIM 512

// per-chain LDS region: exchange1 needs <=568 slots, exchange2 <=652; pad to 656
#define REG_SZ 656

// ---------- complex helpers (float2 = {re, im}) ----------
__device__ __forceinline__ float2 cadd(float2 a, float2 b){ return make_float2(a.x+b.x, a.y+b.y); }
__device__ __forceinline__ float2 csub(float2 a, float2 b){ return make_float2(a.x-b.x, a.y-b.y); }
__device__ __forceinline__ float2 cmul(float2 a, float2 b){
  return make_float2(fmaf(a.x, b.x, -(a.y*b.y)), fmaf(a.x, b.y, a.y*b.x));
}
__device__ __forceinline__ float2 cmulc(float2 a, float2 b){ // a * conj(b)
  return make_float2(fmaf(a.x, b.x, a.y*b.y), fmaf(a.y, b.x, -(a.x*b.y)));
}
__device__ __forceinline__ float2 mul_mi(float2 a){ return make_float2(a.y, -a.x); } // a * (-i)

// 8-point DFT, natural in / natural out, W = exp(-2*pi*i/8)
__device__ __forceinline__ void dft8(const float2* in, float2* out){
  float2 t0 = cadd(in[0], in[4]), t1 = csub(in[0], in[4]);
  float2 t2 = cadd(in[2], in[6]), t3 = csub(in[2], in[6]);
  float2 E0 = cadd(t0, t2), E2 = csub(t0, t2);
  float2 m3 = mul_mi(t3);
  float2 E1 = cadd(t1, m3), E3 = csub(t1, m3);
  float2 s0 = cadd(in[1], in[5]), s1 = csub(in[1], in[5]);
  float2 s2 = cadd(in[3], in[7]), s3 = csub(in[3], in[7]);
  float2 O0 = cadd(s0, s2), O2 = csub(s0, s2);
  float2 n3 = mul_mi(s3);
  float2 O1 = cadd(s1, n3), O3 = csub(s1, n3);
  const float C = 0.70710678118654752440f;
  float2 w1o = make_float2(C*(O1.x + O1.y), C*(O1.y - O1.x));   // W8^1 * O1
  float2 w2o = mul_mi(O2);                                       // W8^2 * O2
  float2 w3o = make_float2(C*(O3.y - O3.x), -(C*(O3.x + O3.y))); // W8^3 * O3
  out[0] = cadd(E0, O0); out[4] = csub(E0, O0);
  out[1] = cadd(E1, w1o); out[5] = csub(E1, w1o);
  out[2] = cadd(E2, w2o); out[6] = csub(E2, w2o);
  out[3] = cadd(E3, w3o); out[7] = csub(E3, w3o);
}

// unscaled inverse 8-pt DFT: IDFT(a)[k] == DFT(a)[(-k) mod 8]
__device__ __forceinline__ void idft8(const float2* in, float2* out){
  float2 t[8];
  dft8(in, t);
  out[0]=t[0]; out[1]=t[7]; out[2]=t[6]; out[3]=t[5];
  out[4]=t[4]; out[5]=t[3]; out[6]=t[2]; out[7]=t[1];
}

// Exchange addressing (bank-pair = idx mod 16 bijective per 16-lane phase):
//   exchange1: write 72*r + lane ; read 72*a + b + 8*j   (conflict-free)
//   exchange2: f2 = a + 82*u + 10*w                      (conflict-free)

// ---------- single-chain 512-pt forward FFT (used for the p spectrum) ----
__device__ __forceinline__ void fft512_fwd(float2* v, float2* lds, int lane,
                                           const float2* wA, const float2* wB){
  const int a = lane >> 3, b = lane & 7;
  float2 t[8];
  dft8(v, t);
  #pragma unroll
  for (int r = 1; r < 8; ++r) t[r] = cmul(t[r], wA[r]);
  __syncthreads();
  #pragma unroll
  for (int r = 0; r < 8; ++r) lds[72*r + lane] = t[r];
  __syncthreads();
  #pragma unroll
  for (int j2 = 0; j2 < 8; ++j2) v[j2] = lds[72*a + b + 8*j2];
  dft8(v, t);
  #pragma unroll
  for (int r2 = 1; r2 < 8; ++r2) t[r2] = cmul(t[r2], wB[r2]);
  __syncthreads();
  #pragma unroll
  for (int r2 = 0; r2 < 8; ++r2) lds[a + 82*r2 + 10*b] = t[r2];
  __syncthreads();
  #pragma unroll
  for (int i2 = 0; i2 < 8; ++i2) v[i2] = lds[a + 82*b + 10*i2];
  dft8(v, t);
  #pragma unroll
  for (int m = 0; m < 8; ++m) v[m] = t[m];
}

// ---------- dual-chain forward FFT: two independent 512-pt FFTs ----------
// Chain B's VALU covers chain A's LDS latency (DS ops retire in order, so
// waiting on chain B's reads implies chain A's writes completed).
__device__ __forceinline__ void fft512_fwd2(float2* va, float2* vb,
                                            float2* ldsA, float2* ldsB, int lane,
                                            const float2* wA, const float2* wB){
  const int a = lane >> 3, b = lane & 7;
  float2 ta[8], tb[8];
  dft8(va, ta);
  #pragma unroll
  for (int r = 1; r < 8; ++r) ta[r] = cmul(ta[r], wA[r]);
  dft8(vb, tb);
  #pragma unroll
  for (int r = 1; r < 8; ++r) tb[r] = cmul(tb[r], wA[r]);
  __syncthreads();
  #pragma unroll
  for (int r = 0; r < 8; ++r){ ldsA[72*r + lane] = ta[r]; ldsB[72*r + lane] = tb[r]; }
  __syncthreads();
  #pragma unroll
  for (int j2 = 0; j2 < 8; ++j2){ va[j2] = ldsA[72*a + b + 8*j2]; vb[j2] = ldsB[72*a + b + 8*j2]; }
  dft8(va, ta);
  #pragma unroll
  for (int r2 = 1; r2 < 8; ++r2) ta[r2] = cmul(ta[r2], wB[r2]);
  dft8(vb, tb);
  #pragma unroll
  for (int r2 = 1; r2 < 8; ++r2) tb[r2] = cmul(tb[r2], wB[r2]);
  __syncthreads();
  #pragma unroll
  for (int r2 = 0; r2 < 8; ++r2){ ldsA[a + 82*r2 + 10*b] = ta[r2]; ldsB[a + 82*r2 + 10*b] = tb[r2]; }
  __syncthreads();
  #pragma unroll
  for (int i2 = 0; i2 < 8; ++i2){ va[i2] = ldsA[a + 82*b + 10*i2]; vb[i2] = ldsB[a + 82*b + 10*i2]; }
  dft8(va, ta); dft8(vb, tb);
  #pragma unroll
  for (int m = 0; m < 8; ++m){ va[m] = ta[m]; vb[m] = tb[m]; }
}

// ---------- dual-chain inverse FFT (digit-reversed in, natural*512 out) ---
__device__ __forceinline__ void fft512_inv2(float2* va, float2* vb,
                                            float2* ldsA, float2* ldsB, int lane,
                                            const float2* wA, const float2* wB){
  const int a = lane >> 3, b = lane & 7;
  float2 ta[8], tb[8];
  idft8(va, ta); idft8(vb, tb);
  __syncthreads();
  #pragma unroll
  for (int i2 = 0; i2 < 8; ++i2){ ldsA[a + 82*b + 10*i2] = ta[i2]; ldsB[a + 82*b + 10*i2] = tb[i2]; }
  __syncthreads();
  #pragma unroll
  for (int r2 = 0; r2 < 8; ++r2){ va[r2] = ldsA[a + 82*r2 + 10*b]; vb[r2] = ldsB[a + 82*r2 + 10*b]; }
  #pragma unroll
  for (int r2 = 1; r2 < 8; ++r2) va[r2] = cmulc(va[r2], wB[r2]);
  idft8(va, ta);
  #pragma unroll
  for (int r2 = 1; r2 < 8; ++r2) vb[r2] = cmulc(vb[r2], wB[r2]);
  idft8(vb, tb);
  __syncthreads();
  #pragma unroll
  for (int j2 = 0; j2 < 8; ++j2){ ldsA[72*a + b + 8*j2] = ta[j2]; ldsB[72*a + b + 8*j2] = tb[j2]; }
  __syncthreads();
  #pragma unroll
  for (int r = 0; r < 8; ++r){ va[r] = ldsA[72*r + lane]; vb[r] = ldsB[72*r + lane]; }
  #pragma unroll
  for (int r = 1; r < 8; ++r) va[r] = cmulc(va[r], wA[r]);
  idft8(va, ta);
  #pragma unroll
  for (int r = 1; r < 8; ++r) vb[r] = cmulc(vb[r], wA[r]);
  idft8(vb, tb);
  #pragma unroll
  for (int j = 0; j < 8; ++j){ va[j] = ta[j]; vb[j] = tb[j]; }
}

// One wave per block. Wave g handles (s = g>>1, batch rows half*8..half*8+7):
// 2 super-iterations, each = 2 interleaved complex-packed conv chains.
__global__ void __launch_bounds__(64, 4)
circconv_kernel(const float* __restrict__ x, const float* __restrict__ p,
                float* __restrict__ out){
  __shared__ float2 ldsA[REG_SZ];
  __shared__ float2 ldsB[REG_SZ];
  const int lane = threadIdx.x;
  const int g    = blockIdx.x;
  const int s    = g >> 1;
  const int half = g & 1;
  const int b    = lane & 7;

  // lane-only twiddles, computed once per wave
  float2 wA[8], wB[8];
  wA[0] = make_float2(1.f, 0.f); wB[0] = make_float2(1.f, 0.f);
  #pragma unroll
  for (int r = 1; r < 8; ++r){
    float sv, cv;
    sincosf(-2.0f*(float)M_PI*(float)(lane*r)*(1.0f/512.0f), &sv, &cv);
    wA[r] = make_float2(cv, sv);
    sincosf(-2.0f*(float)M_PI*(float)(b*r)*(1.0f/64.0f), &sv, &cv);
    wB[r] = make_float2(cv, sv);
  }

  // Issue first super-iteration's 32 x-loads NOW so they ride under the p-FFT.
  const int b_lo = half * 8;
  const size_t sbase = (size_t)s * DIM + lane;
  float2 va[8], vb[8];
  {
    const size_t r0 = ((size_t)(b_lo+0) * SEQ) * DIM + sbase;
    const size_t r1 = ((size_t)(b_lo+1) * SEQ) * DIM + sbase;
    const size_t r2 = ((size_t)(b_lo+2) * SEQ) * DIM + sbase;
    const size_t r3 = ((size_t)(b_lo+3) * SEQ) * DIM + sbase;
    #pragma unroll
    for (int j = 0; j < 8; ++j){
      va[j] = make_float2(x[r0 + 64*j], x[r1 + 64*j]);
      vb[j] = make_float2(x[r2 + 64*j], x[r3 + 64*j]);
    }
  }

  // P spectrum for this s, scaled by 1/512 (x-loads above stay in flight)
  float2 pf[8];
  {
    const float* prow = p + (size_t)s * DIM;
    #pragma unroll
    for (int j = 0; j < 8; ++j) pf[j] = make_float2(prow[lane + 64*j], 0.f);
    fft512_fwd(pf, ldsA, lane, wA, wB);
    #pragma unroll
    for (int m = 0; m < 8; ++m){ pf[m].x *= (1.0f/512.0f); pf[m].y *= (1.0f/512.0f); }
  }

  #pragma unroll
  for (int q = 0; q < 2; ++q){
    const int bb = b_lo + 4*q;
    const size_t r0 = ((size_t)(bb+0) * SEQ) * DIM + sbase;
    const size_t r1 = ((size_t)(bb+1) * SEQ) * DIM + sbase;
    const size_t r2 = ((size_t)(bb+2) * SEQ) * DIM + sbase;
    const size_t r3 = ((size_t)(bb+3) * SEQ) * DIM + sbase;
    if (q > 0){
      #pragma unroll
      for (int j = 0; j < 8; ++j){
        va[j] = make_float2(x[r0 + 64*j], x[r1 + 64*j]);
        vb[j] = make_float2(x[r2 + 64*j], x[r3 + 64*j]);
      }
    }
    fft512_fwd2(va, vb, ldsA, ldsB, lane, wA, wB);
    #pragma unroll
    for (int m = 0; m < 8; ++m){ va[m] = cmul(va[m], pf[m]); vb[m] = cmul(vb[m], pf[m]); }
    fft512_inv2(va, vb, ldsA, ldsB, lane, wA, wB);
    #pragma unroll
    for (int j = 0; j < 8; ++j){
      out[r0 + 64*j] = va[j].x;
      out[r1 + 64*j] = va[j].y;
      out[r2 + 64*j] = vb[j].x;
      out[r3 + 64*j] = vb[j].y;
    }
  }
}

extern "C" void kernel_launch(void* const* d_in, const int* in_sizes, int n_in,
                              void* d_out, int out_size, void* d_ws, size_t ws_size,
                              hipStream_t stream) {
  (void)in_sizes; (void)n_in; (void)d_ws; (void)ws_size; (void)out_size;
  const float* x  = (const float*)d_in[0];
  const float* p  = (const float*)d_in[1];
  float* o        = (float*)d_out;
  circconv_kernel<<<SEQ*2, 64, 0, stream>>>(x, p, o);
}